// Round 11
// baseline (359.898 us; speedup 1.0000x reference)
//
#include <hip/hip_runtime.h>
#include <hip/hip_bf16.h>
#include <math.h>

typedef __attribute__((ext_vector_type(8))) unsigned short ushort8;
typedef __attribute__((ext_vector_type(8))) __bf16 bf16x8;
typedef __attribute__((ext_vector_type(4))) float floatx4;

constexpr int IMGW = 384;
constexpr int NPIX = IMGW * IMGW;

__device__ __forceinline__ unsigned short f2bf(float f) {
  union { float f; unsigned u; } v; v.f = f;
  unsigned u = v.u;
  return (unsigned short)((u + 0x7fffu + ((u >> 16) & 1u)) >> 16);
}
__device__ __forceinline__ float bf2f(unsigned short h) {
  union { unsigned u; float f; } v; v.u = ((unsigned)h) << 16; return v.f;
}
// pack 2 fp32 -> 2 bf16 (RNE): v_cvt_pk_bf16_f32
__device__ __forceinline__ unsigned pk2bf(float a, float b) {
  float2 f2; f2.x = a; f2.y = b;
  __hip_bfloat162 h = __float22bfloat162_rn(f2);
  union { __hip_bfloat162 h; unsigned u; } u; u.h = h; return u.u;
}
__device__ __forceinline__ floatx4 mfma16(bf16x8 a, bf16x8 b, floatx4 c) {
  return __builtin_amdgcn_mfma_f32_16x16x32_bf16(a, b, c, 0, 0, 0);
}
__device__ __forceinline__ bf16x8 lds_frag(const unsigned short* p) {
  return *reinterpret_cast<const bf16x8*>(p);
}
__device__ __forceinline__ bf16x8 u4_to_bf(uint4 v) {
  union { uint4 u; bf16x8 b; } c; c.u = v; return c.b;
}

// ---------------- weight prep: MLP A-operand, swizzle-packed, permuted-k ----
__global__ void prep_mlpA(const float* __restrict__ w1, const float* __restrict__ w2,
                          const float* __restrict__ w3,
                          unsigned short* __restrict__ w1A, unsigned short* __restrict__ w2A,
                          unsigned short* __restrict__ w3A) {
  int i = blockIdx.x * 256 + threadIdx.x;
  if (i < 8192) {                       // w1A: M=128 (mt 8), KS=2
    int j = i & 7, lane = (i >> 3) & 63, t = i >> 9;
    int mt = t >> 1, ks = t & 1;
    int ch_out = mt * 16 + (lane & 15);
    int kp = ks * 32 + (lane >> 4) * 8 + j;
    int chunk = kp >> 3, sl = kp & 7;
    float val;
    if (chunk == 7 && sl >= 4) {
      int c = sl - 4;
      val = (c < 3) ? w1[c * 128 + ch_out] : 0.0f;   // raw x,y,z,pad
    } else {
      const int coordA[8] = {0,0,0,1,1,2,2,2};
      const int octA[8]   = {0,4,8,2,6,0,4,8};
      const int coordB[8] = {0,0,1,1,1,2,2,2};
      const int octB[8]   = {2,6,0,4,8,2,6,0};
      int rc  = (sl < 4) ? coordA[chunk] : coordB[chunk];
      int oct = ((sl < 4) ? octA[chunk] : octB[chunk]) + ((sl >> 1) & 1);
      int korig = ((sl & 1) ? 33 : 3) + rc * 10 + oct;
      val = w1[korig * 128 + ch_out];
    }
    w1A[i] = f2bf(val);
  } else if (i < 24576) {               // w2A: M=128 (mt 8), KS=4, permuted k
    int i2 = i - 8192;
    int j = i2 & 7, lane = (i2 >> 3) & 63, t = i2 >> 9;
    int mt = t >> 2, ks = t & 3;
    int ch_out = mt * 16 + (lane & 15);
    int kp = ks * 32 + (lane >> 4) * 8 + j;
    int c_orig = ((kp >> 2) & 7) * 16 + (kp >> 5) * 4 + (kp & 3);
    w2A[i2] = f2bf(w2[c_orig * 128 + ch_out]);
  } else if (i < 28672) {               // w3A: M=32 (mt 2), KS=4, permuted k
    int i3 = i - 24576;
    int j = i3 & 7, lane = (i3 >> 3) & 63, t = i3 >> 9;
    int mt = t >> 2, ks = t & 3;
    int ch_out = mt * 16 + (lane & 15);
    int kp = ks * 32 + (lane >> 4) * 8 + j;
    int c_orig = ((kp >> 2) & 7) * 16 + (kp >> 5) * 4 + (kp & 3);
    w3A[i3] = f2bf(w3[c_orig * 32 + ch_out]);
  }
}

// OIHW fp32 -> swizzled conv B: flat idx = ((ks*G + g)*NT + nt)*512 + lane*8 + j
__global__ void prep_convB(const float* __restrict__ w, unsigned short* __restrict__ wt,
                           int total, int CIN, int G, int NT) {
  int i = blockIdx.x * 256 + threadIdx.x;
  if (i >= total) return;
  int j = i & 7, lane = (i >> 3) & 63;
  int rest = i >> 9;
  int nt = rest % NT; int rest2 = rest / NT;
  int g = rest2 % G;  int ks = rest2 / G;
  int q = lane >> 4, m = lane & 15;
  int co = (g * NT + nt) * 16 + m;
  int k = ks * 32 + q * 8 + j;
  int nb = k / CIN, ci = k - nb * CIN;
  wt[i] = f2bf(w[(co * CIN + ci) * 9 + nb]);
}

// ---------------- per-pixel dir-PE contribution: dconG[pixel][32] ----------------
__global__ __launch_bounds__(256) void dcon_kernel(
    const float* __restrict__ ray, const float* __restrict__ w3,
    const float* __restrict__ b3, float* __restrict__ dconG) {
  int gid = blockIdx.x * 256 + threadIdx.x;
  int pixel = gid >> 5, c = gid & 31;
  const float* r = ray + (size_t)pixel * 7;
  float d0 = r[3], d1 = r[4], d2 = r[5];
  float acc = b3[c];
  acc += d0 * w3[128 * 32 + c] + d1 * w3[129 * 32 + c] + d2 * w3[130 * 32 + c];
  float dv[3] = { d0, d1, d2 };
  #pragma unroll
  for (int cc = 0; cc < 3; ++cc) {
    float fs = 1.0f;
    #pragma unroll
    for (int f = 0; f < 4; ++f) {
      float s, co;
      __sincosf(dv[cc] * fs, &s, &co);
      acc += s * w3[(131 + cc * 4 + f) * 32 + c];
      acc += co * w3[(143 + cc * 4 + f) * 32 + c];
      fs *= 2.0f;
    }
  }
  dconG[gid] = acc;
}

// ---------------- fused per-sample MLP: 64 samples/WAVE, mt-halved layers ----
// 64 thr (1 wave), 64 samples/block. Weight A-fragment loads (56/wave, 1KiB
// each) now serve 64 samples instead of 32 -> L2 weight traffic per sample
// halves (R10 analysis: ~29 of 68 µs was L2 weight-fragment bandwidth).
// Output channels processed in two mt-halves so live acc is only acc[4][4]
// (64 VGPR; R9 lesson: acc[8][4]=128 spills). Same k-permutation / packing /
// epilogue col' layout as R7-R10. H = 64*136*2 = 17408 B.
__global__ __launch_bounds__(64, 3) void mlp_kernel(
    const float* __restrict__ zbufs, const float* __restrict__ ray,
    const int* __restrict__ isTrain,
    const float* __restrict__ b1, const float* __restrict__ b2,
    const unsigned short* __restrict__ w1A, const unsigned short* __restrict__ w2A,
    const unsigned short* __restrict__ w3A, const float* __restrict__ dconG,
    unsigned short* __restrict__ rdmp) {
  __shared__ __align__(16) unsigned short H[64 * 136];

  const int lane = threadIdx.x;
  const int q = lane >> 4, m = lane & 15;
  const float thresh = (isTrain[0] != 0) ? 0.2f : 0.0f;

  float fA[2], fB[2];
  int cAi[2], cBi[2];
  #pragma unroll
  for (int half = 0; half < 2; ++half) {
    int ch = half * 4 + q;
    cAi[half] = (ch <= 2) ? 0 : ((ch <= 4) ? 1 : 2);
    fA[half]  = (ch == 0 || ch == 5) ? 1.0f :
                (ch == 1 || ch == 6) ? 16.0f :
                (ch == 2 || ch == 7) ? 256.0f :
                (ch == 3) ? 4.0f : 64.0f;
    cBi[half] = (ch <= 1) ? 0 : ((ch <= 4) ? 1 : 2);
    fB[half]  = (ch == 2) ? 1.0f :
                (ch == 0 || ch == 5) ? 4.0f :
                (ch == 3) ? 16.0f :
                (ch == 1 || ch == 6) ? 64.0f : 256.0f;
  }

  // phase 0: per-lane B-frag computation for 4 sample tiles
  bf16x8 bx[4][2];
  float zs[4];
  #pragma unroll
  for (int nt = 0; nt < 4; ++nt) {
    int s = nt * 16 + m;
    int sg = blockIdx.x * 64 + s;
    int pixel = sg >> 2;
    float z = zbufs[sg];
    zs[nt] = z;
    const float* r = ray + (size_t)pixel * 7;
    float t = z / r[6];
    float xv0 = r[0] + r[3] * t, xv1 = r[1] + r[4] * t, xv2 = r[2] + r[5] * t;
    #pragma unroll
    for (int half = 0; half < 2; ++half) {
      float uA = (cAi[half] == 0) ? xv0 : ((cAi[half] == 1) ? xv1 : xv2);
      float uB = (cBi[half] == 0) ? xv0 : ((cBi[half] == 1) ? xv1 : xv2);
      float sa, ca, sb, cb;
      __sincosf(uA * fA[half], &sa, &ca);
      __sincosf(uB * fB[half], &sb, &cb);
      float t2a = sa + sa;
      float sa1 = t2a * ca, ca1 = fmaf(-t2a, sa, 1.0f);
      float t2b = sb + sb;
      float sb1 = t2b * cb, cb1 = fmaf(-t2b, sb, 1.0f);
      if (half == 1 && q == 3) { sb = xv0; cb = xv1; sb1 = xv2; cb1 = 0.0f; }
      uint4 dv;
      dv.x = pk2bf(sa, ca); dv.y = pk2bf(sa1, ca1);
      dv.z = pk2bf(sb, cb); dv.w = pk2bf(sb1, cb1);
      bx[nt][half] = u4_to_bf(dv);
    }
  }

  // ---- layer 1: D^T = w1A(128x64) x X(B, in regs), mt-halved ----
  #pragma unroll 1
  for (int half = 0; half < 2; ++half) {
    floatx4 acc[4][4];
    #pragma unroll
    for (int mt = 0; mt < 4; ++mt) {
      float4 bb = *reinterpret_cast<const float4*>(b1 + (half * 4 + mt) * 16 + q * 4);
      #pragma unroll
      for (int nt = 0; nt < 4; ++nt) {
        acc[mt][nt][0] = bb.x; acc[mt][nt][1] = bb.y;
        acc[mt][nt][2] = bb.z; acc[mt][nt][3] = bb.w;
      }
    }
    #pragma unroll
    for (int ks = 0; ks < 2; ++ks) {
      #pragma unroll
      for (int mt = 0; mt < 4; ++mt) {
        int mtg = half * 4 + mt;
        bf16x8 a = *reinterpret_cast<const bf16x8*>(w1A + (((mtg << 1) + ks) << 9) + lane * 8);
        #pragma unroll
        for (int nt = 0; nt < 4; ++nt)
          acc[mt][nt] = mfma16(a, bx[nt][ks], acc[mt][nt]);
      }
    }
    // epilogue: col' = q*32 + half*16 + g*8 + e*4 + r  (mt_g = half*4+2g+e)
    #pragma unroll
    for (int nt = 0; nt < 4; ++nt) {
      uint4* base = reinterpret_cast<uint4*>(&H[(nt * 16 + m) * 136 + q * 32 + half * 16]);
      #pragma unroll
      for (int g = 0; g < 2; ++g) {
        uint4 v;
        v.x = pk2bf(fmaxf(acc[2*g][nt][0], 0.0f),   fmaxf(acc[2*g][nt][1], 0.0f));
        v.y = pk2bf(fmaxf(acc[2*g][nt][2], 0.0f),   fmaxf(acc[2*g][nt][3], 0.0f));
        v.z = pk2bf(fmaxf(acc[2*g+1][nt][0], 0.0f), fmaxf(acc[2*g+1][nt][1], 0.0f));
        v.w = pk2bf(fmaxf(acc[2*g+1][nt][2], 0.0f), fmaxf(acc[2*g+1][nt][3], 0.0f));
        base[g] = v;
      }
    }
  }

  // ---- layer 2: D^T = w2A(128x128) x H1(B), mt-halved, in place ----
  // Write to upper-half col' only after all reads of that region? Reads span
  // full col' range each half — but rows are lane-private per nt? NO: reads
  // are per-lane rows (nt*16+m) — same rows written. In-wave LDS ops are
  // in-order per lane&address; the half-0 epilogue writes col' [q*32, q*32+16)
  // while half-1 reads col' [ks*32+q*8, +8) of the SAME rows — these ranges
  // overlap only if the half-1 read needs half-0's OUTPUT, which it doesn't:
  // reads source H1 (layer-1 output) which is fully written before layer 2
  // (same wave, in-order). Half-0's layer-2 epilogue overwrites col' regions
  // that half-1's reads still need! -> stage half-0 output in regs, write
  // both halves' outputs after the loop.
  {
    uint4 keep[4][2];          // half-0 epilogue staged (32 VGPR)
    #pragma unroll 1
    for (int half = 0; half < 2; ++half) {
      floatx4 acc[4][4];
      #pragma unroll
      for (int mt = 0; mt < 4; ++mt) {
        float4 bb = *reinterpret_cast<const float4*>(b2 + (half * 4 + mt) * 16 + q * 4);
        #pragma unroll
        for (int nt = 0; nt < 4; ++nt) {
          acc[mt][nt][0] = bb.x; acc[mt][nt][1] = bb.y;
          acc[mt][nt][2] = bb.z; acc[mt][nt][3] = bb.w;
        }
      }
      #pragma unroll 1
      for (int ks = 0; ks < 4; ++ks) {
        bf16x8 bf[4];
        #pragma unroll
        for (int nt = 0; nt < 4; ++nt)
          bf[nt] = lds_frag(H + (nt * 16 + m) * 136 + ks * 32 + q * 8);
        #pragma unroll
        for (int mt = 0; mt < 4; ++mt) {
          int mtg = half * 4 + mt;
          bf16x8 a = *reinterpret_cast<const bf16x8*>(w2A + (((mtg << 2) + ks) << 9) + lane * 8);
          #pragma unroll
          for (int nt = 0; nt < 4; ++nt)
            acc[mt][nt] = mfma16(a, bf[nt], acc[mt][nt]);
        }
      }
      #pragma unroll
      for (int nt = 0; nt < 4; ++nt) {
        #pragma unroll
        for (int g = 0; g < 2; ++g) {
          uint4 v;
          v.x = pk2bf(fmaxf(acc[2*g][nt][0], 0.0f),   fmaxf(acc[2*g][nt][1], 0.0f));
          v.y = pk2bf(fmaxf(acc[2*g][nt][2], 0.0f),   fmaxf(acc[2*g][nt][3], 0.0f));
          v.z = pk2bf(fmaxf(acc[2*g+1][nt][0], 0.0f), fmaxf(acc[2*g+1][nt][1], 0.0f));
          v.w = pk2bf(fmaxf(acc[2*g+1][nt][2], 0.0f), fmaxf(acc[2*g+1][nt][3], 0.0f));
          if (half == 0) {
            keep[nt][g] = v;
          } else {
            *reinterpret_cast<uint4*>(&H[(nt * 16 + m) * 136 + q * 32 + 16 + g * 8]) = v;
          }
        }
      }
    }
    #pragma unroll
    for (int nt = 0; nt < 4; ++nt)
      #pragma unroll
      for (int g = 0; g < 2; ++g)
        *reinterpret_cast<uint4*>(&H[(nt * 16 + m) * 136 + q * 32 + g * 8]) = keep[nt][g];
  }

  // ---- layer 3: D^T = w3A(32x128) x H2(B) (+dcon init), mask, NHWC ----
  {
    floatx4 acc[2][4];
    const float* dg = dconG + (size_t)blockIdx.x * 512;
    #pragma unroll
    for (int nt = 0; nt < 4; ++nt) {
      int s = nt * 16 + m;
      #pragma unroll
      for (int mt = 0; mt < 2; ++mt)
        acc[mt][nt] = *reinterpret_cast<const floatx4*>(dg + (s >> 2) * 32 + mt * 16 + q * 4);
    }
    #pragma unroll 2
    for (int ks = 0; ks < 4; ++ks) {
      bf16x8 bf[4];
      #pragma unroll
      for (int nt = 0; nt < 4; ++nt)
        bf[nt] = lds_frag(H + (nt * 16 + m) * 136 + ks * 32 + q * 8);
      #pragma unroll
      for (int mt = 0; mt < 2; ++mt) {
        bf16x8 a = *reinterpret_cast<const bf16x8*>(w3A + (((mt << 2) + ks) << 9) + lane * 8);
        #pragma unroll
        for (int nt = 0; nt < 4; ++nt)
          acc[mt][nt] = mfma16(a, bf[nt], acc[mt][nt]);
      }
    }
    #pragma unroll
    for (int nt = 0; nt < 4; ++nt) {
      int s = nt * 16 + m;
      float mk = (zs[nt] > thresh) ? 1.0f : 0.0f;
      unsigned short* dst = rdmp + (size_t)blockIdx.x * 2048 + s * 32 + q * 4;
      #pragma unroll
      for (int mt = 0; mt < 2; ++mt) {
        uint2 pk;
        pk.x = pk2bf(acc[mt][nt][0] * mk, acc[mt][nt][1] * mk);
        pk.y = pk2bf(acc[mt][nt][2] * mk, acc[mt][nt][3] * mk);
        *reinterpret_cast<uint2*>(dst + mt * 16) = pk;
      }
    }
  }
}

// ---------------- NHWC 3x3 conv via MFMA, 16x8 tile, dx-outer ----------------
// (R10 known-good) 4 waves, each owns COUT/4 couts over all 8 rows.
// Per (kc,dx): a[10] halo (40 VGPR), unrolled dy x nt; each B feeds 8 MFMAs.
template<int CIN, int COUT, int MODE>
__global__ __launch_bounds__(256, 2) void conv3x3(
    const unsigned short* __restrict__ in, const unsigned short* __restrict__ wt,
    const float* __restrict__ bias, const unsigned short* __restrict__ rdmp,
    unsigned short* __restrict__ out) {
  constexpr int CP  = CIN + 8;
  constexpr int CH8 = CIN / 8;
  constexpr int KC  = CIN / 32;
  constexpr int NT  = COUT / 64;
  __shared__ __align__(16) unsigned short lds_in[10 * 18 * CP];

  const int tid = threadIdx.x;
  const int x0 = blockIdx.x * 16, y0 = blockIdx.y * 8;

  for (int i = tid; i < 180 * CH8; i += 256) {
    int pix = i / CH8, part = i - pix * CH8;
    int xx = pix % 18, yy = pix / 18;
    int gx = x0 - 1 + xx, gy = y0 - 1 + yy;
    ushort8 v = {0, 0, 0, 0, 0, 0, 0, 0};
    if (gx >= 0 && gx < IMGW && gy >= 0 && gy < IMGW)
      v = *reinterpret_cast<const ushort8*>(in + ((size_t)(gy * IMGW + gx)) * CIN + part * 8);
    *reinterpret_cast<ushort8*>(&lds_in[pix * CP + part * 8]) = v;
  }
  __syncthreads();

  const int wave = tid >> 6, lane = tid & 63, q = lane >> 4, m = lane & 15;
  floatx4 acc[8][NT] = {};

  #pragma unroll 1
  for (int kc = 0; kc < KC; ++kc) {
    #pragma unroll 1
    for (int dx = 0; dx < 3; ++dx) {
      bf16x8 a[10];
      #pragma unroll
      for (int rr = 0; rr < 10; ++rr)
        a[rr] = lds_frag(&lds_in[(rr * 18 + m + dx) * CP + kc * 32 + q * 8]);
      #pragma unroll
      for (int dy = 0; dy < 3; ++dy) {
        int ks = (dy * 3 + dx) * KC + kc;
        #pragma unroll
        for (int nt = 0; nt < NT; ++nt) {
          bf16x8 b = *reinterpret_cast<const bf16x8*>(
              wt + ((((size_t)ks * 4 + wave) * NT + nt) << 9) + lane * 8);
          #pragma unroll
          for (int mt = 0; mt < 8; ++mt)
            acc[mt][nt] = mfma16(a[mt + dy], b, acc[mt][nt]);
        }
      }
    }
  }

  const int co0 = wave * (COUT / 4);
  #pragma unroll
  for (int mt = 0; mt < 8; ++mt) {
    int y = y0 + mt;
    #pragma unroll
    for (int nt = 0; nt < NT; ++nt) {
      int co = co0 + nt * 16 + m;
      float bb = bias[co];
      #pragma unroll
      for (int r = 0; r < 4; ++r) {
        int pixel = y * IMGW + x0 + q * 4 + r;
        float v = acc[mt][nt][r] + bb;
        if (MODE == 0) {
          v = fmaxf(v, 0.0f);
        } else {
          v = 1.0f / (1.0f + __expf(-v));
          v *= bf2f(rdmp[(size_t)pixel * 128 + co]);
        }
        out[(size_t)pixel * COUT + co] = f2bf(v);
      }
    }
  }
}

// ---------------- final 64->3 conv + sigmoid, fp32 NHWC out ----------------
__global__ __launch_bounds__(256) void uconv3_kernel(
    const unsigned short* __restrict__ u2, const float* __restrict__ w,
    const float* __restrict__ b, float* __restrict__ out) {
  __shared__ float wl[1728];   // [nb][ci][c]
  for (int i = threadIdx.x; i < 1728; i += 256) {
    int c = i % 3; int t = i / 3; int ci = t & 63; int nb = t >> 6;
    wl[i] = w[(c * 64 + ci) * 9 + nb];
  }
  __syncthreads();
  int pixel = blockIdx.x * 256 + threadIdx.x;
  int py = pixel / IMGW, px = pixel - py * IMGW;
  float a0 = b[0], a1 = b[1], a2 = b[2];
  for (int nb = 0; nb < 9; ++nb) {
    int gy = py + nb / 3 - 1, gx = px + nb % 3 - 1;
    if (gx < 0 || gx >= IMGW || gy < 0 || gy >= IMGW) continue;
    const unsigned short* src = u2 + (size_t)(gy * IMGW + gx) * 64;
    const float* wp = wl + nb * 192;
    #pragma unroll
    for (int cc = 0; cc < 8; ++cc) {
      ushort8 v = *reinterpret_cast<const ushort8*>(src + cc * 8);
      #pragma unroll
      for (int j = 0; j < 8; ++j) {
        float uv = bf2f(v[j]);
        const float* w3p = wp + (cc * 8 + j) * 3;
        a0 += uv * w3p[0]; a1 += uv * w3p[1]; a2 += uv * w3p[2];
      }
    }
  }
  float* o = out + (size_t)pixel * 3;
  o[0] = 1.0f / (1.0f + __expf(-a0));
  o[1] = 1.0f / (1.0f + __expf(-a1));
  o[2] = 1.0f / (1.0f + __expf(-a2));
}

extern "C" void kernel_launch(void* const* d_in, const int* in_sizes, int n_in,
                              void* d_out, int out_size, void* d_ws, size_t ws_size,
                              hipStream_t stream) {
  (void)in_sizes; (void)n_in; (void)out_size; (void)ws_size;
  const float* zbufs = (const float*)d_in[0];
  const float* ray   = (const float*)d_in[1];
  const int* isTrain = (const int*)d_in[4];
  const float* w1 = (const float*)d_in[6];
  const float* b1 = (const float*)d_in[7];
  const float* w2 = (const float*)d_in[8];
  const float* b2 = (const float*)d_in[9];
  const float* w3 = (const float*)d_in[10];
  const float* b3 = (const float*)d_in[11];
  const float* mpn_w1 = (const float*)d_in[12];
  const float* mpn_b1 = (const float*)d_in[13];
  const float* mpn_w2 = (const float*)d_in[14];
  const float* mpn_b2 = (const float*)d_in[15];
  const float* uw1 = (const float*)d_in[16];
  const float* ub1 = (const float*)d_in[17];
  const float* uw2 = (const float*)d_in[18];
  const float* ub2 = (const float*)d_in[19];
  const float* uw3 = (const float*)d_in[20];
  const float* ub3 = (const float*)d_in[21];
  float* out = (float*)d_out;

  unsigned char* ws = (unsigned char*)d_ws;
  size_t off = 0;
  auto alloc = [&](size_t bytes) -> void* {
    void* p = ws + off; off = (off + bytes + 255) & ~(size_t)255; return p;
  };
  unsigned short* w1A  = (unsigned short*)alloc(8192 * 2);
  unsigned short* w2A  = (unsigned short*)alloc(16384 * 2);
  unsigned short* w3A  = (unsigned short*)alloc(4096 * 2);
  unsigned short* cw1  = (unsigned short*)alloc((size_t)128 * 1152 * 2);
  unsigned short* cw2  = (unsigned short*)alloc((size_t)128 * 1152 * 2);
  unsigned short* cu1  = (unsigned short*)alloc((size_t)64 * 1152 * 2);
  unsigned short* cu2  = (unsigned short*)alloc((size_t)64 * 576 * 2);
  unsigned short* rdmp = (unsigned short*)alloc((size_t)NPIX * 128 * 2);
  unsigned short* t1   = (unsigned short*)alloc((size_t)NPIX * 128 * 2);
  unsigned short* fuse = (unsigned short*)alloc((size_t)NPIX * 128 * 2);
  unsigned short* u1 = t1;            // t1 dead after conv2
  unsigned short* u2 = rdmp;          // rdmp dead after conv2 (fuse epilogue)
  float* dconG = (float*)fuse;        // dconG dead before conv2 writes fuse

  prep_mlpA<<<112, 256, 0, stream>>>(w1, w2, w3, w1A, w2A, w3A);
  prep_convB<<<576, 256, 0, stream>>>(mpn_w1, cw1, 128 * 1152, 128, 4, 2);
  prep_convB<<<576, 256, 0, stream>>>(mpn_w2, cw2, 128 * 1152, 128, 4, 2);
  prep_convB<<<288, 256, 0, stream>>>(uw1, cu1, 64 * 1152, 128, 4, 1);
  prep_convB<<<144, 256, 0, stream>>>(uw2, cu2, 64 * 576, 64, 4, 1);

  dcon_kernel<<<NPIX * 32 / 256, 256, 0, stream>>>(ray, w3, b3, dconG);
  mlp_kernel<<<NPIX * 4 / 64, 64, 0, stream>>>(zbufs, ray, isTrain, b1, b2,
                                               w1A, w2A, w3A, dconG, rdmp);

  dim3 cgrid(IMGW / 16, IMGW / 8);
  conv3x3<128, 128, 0><<<cgrid, 256, 0, stream>>>(rdmp, cw1, mpn_b1, nullptr, t1);
  conv3x3<128, 128, 1><<<cgrid, 256, 0, stream>>>(t1, cw2, mpn_b2, rdmp, fuse);
  conv3x3<128, 64, 0><<<cgrid, 256, 0, stream>>>(fuse, cu1, ub1, nullptr, u1);
  conv3x3<64, 64, 0><<<cgrid, 256, 0, stream>>>(u1, cu2, ub2, nullptr, u2);
  uconv3_kernel<<<NPIX / 256, 256, 0, stream>>>(u2, uw3, ub3, out);
}

// Round 12
// 349.252 us; speedup vs baseline: 1.0305x; 1.0305x over previous
//
#include <hip/hip_runtime.h>
#include <hip/hip_bf16.h>
#include <math.h>

typedef __attribute__((ext_vector_type(8))) unsigned short ushort8;
typedef __attribute__((ext_vector_type(8))) __bf16 bf16x8;
typedef __attribute__((ext_vector_type(4))) float floatx4;

constexpr int IMGW = 384;
constexpr int NPIX = IMGW * IMGW;

__device__ __forceinline__ unsigned short f2bf(float f) {
  union { float f; unsigned u; } v; v.f = f;
  unsigned u = v.u;
  return (unsigned short)((u + 0x7fffu + ((u >> 16) & 1u)) >> 16);
}
__device__ __forceinline__ float bf2f(unsigned short h) {
  union { unsigned u; float f; } v; v.u = ((unsigned)h) << 16; return v.f;
}
// pack 2 fp32 -> 2 bf16 (RNE): v_cvt_pk_bf16_f32
__device__ __forceinline__ unsigned pk2bf(float a, float b) {
  float2 f2; f2.x = a; f2.y = b;
  __hip_bfloat162 h = __float22bfloat162_rn(f2);
  union { __hip_bfloat162 h; unsigned u; } u; u.h = h; return u.u;
}
__device__ __forceinline__ floatx4 mfma16(bf16x8 a, bf16x8 b, floatx4 c) {
  return __builtin_amdgcn_mfma_f32_16x16x32_bf16(a, b, c, 0, 0, 0);
}
__device__ __forceinline__ bf16x8 lds_frag(const unsigned short* p) {
  return *reinterpret_cast<const bf16x8*>(p);
}
__device__ __forceinline__ bf16x8 u4_to_bf(uint4 v) {
  union { uint4 u; bf16x8 b; } c; c.u = v; return c.b;
}

// ---------------- fused weight prep (single launch) ----------------
__device__ __forceinline__ void convB_elem(const float* __restrict__ w,
                                           unsigned short* __restrict__ wt,
                                           int i, int CIN, int G, int NT) {
  int j = i & 7, lane = (i >> 3) & 63;
  int rest = i >> 9;
  int nt = rest % NT; int rest2 = rest / NT;
  int g = rest2 % G;  int ks = rest2 / G;
  int q = lane >> 4, m = lane & 15;
  int co = (g * NT + nt) * 16 + m;
  int k = ks * 32 + q * 8 + j;
  int nb = k / CIN, ci = k - nb * CIN;
  wt[i] = f2bf(w[(co * CIN + ci) * 9 + nb]);
}

// jobs (linear index): [0,28672) mlpA | cw1 147456 | cw2 147456 | cu1 73728 | cu2 36864
__global__ __launch_bounds__(256) void prep_all(
    const float* __restrict__ w1, const float* __restrict__ w2, const float* __restrict__ w3,
    const float* __restrict__ mw1, const float* __restrict__ mw2,
    const float* __restrict__ uw1, const float* __restrict__ uw2,
    unsigned short* __restrict__ w1A, unsigned short* __restrict__ w2A,
    unsigned short* __restrict__ w3A,
    unsigned short* __restrict__ cw1, unsigned short* __restrict__ cw2,
    unsigned short* __restrict__ cu1, unsigned short* __restrict__ cu2) {
  int i = blockIdx.x * 256 + threadIdx.x;
  if (i < 28672) {
    if (i < 8192) {                       // w1A: M=128 (mt 8), KS=2
      int j = i & 7, lane = (i >> 3) & 63, t = i >> 9;
      int mt = t >> 1, ks = t & 1;
      int ch_out = mt * 16 + (lane & 15);
      int kp = ks * 32 + (lane >> 4) * 8 + j;
      int chunk = kp >> 3, sl = kp & 7;
      float val;
      if (chunk == 7 && sl >= 4) {
        int c = sl - 4;
        val = (c < 3) ? w1[c * 128 + ch_out] : 0.0f;   // raw x,y,z,pad
      } else {
        const int coordA[8] = {0,0,0,1,1,2,2,2};
        const int octA[8]   = {0,4,8,2,6,0,4,8};
        const int coordB[8] = {0,0,1,1,1,2,2,2};
        const int octB[8]   = {2,6,0,4,8,2,6,0};
        int rc  = (sl < 4) ? coordA[chunk] : coordB[chunk];
        int oct = ((sl < 4) ? octA[chunk] : octB[chunk]) + ((sl >> 1) & 1);
        int korig = ((sl & 1) ? 33 : 3) + rc * 10 + oct;
        val = w1[korig * 128 + ch_out];
      }
      w1A[i] = f2bf(val);
    } else if (i < 24576) {               // w2A: M=128 (mt 8), KS=4, permuted k
      int i2 = i - 8192;
      int j = i2 & 7, lane = (i2 >> 3) & 63, t = i2 >> 9;
      int mt = t >> 2, ks = t & 3;
      int ch_out = mt * 16 + (lane & 15);
      int kp = ks * 32 + (lane >> 4) * 8 + j;
      int c_orig = ((kp >> 2) & 7) * 16 + (kp >> 5) * 4 + (kp & 3);
      w2A[i2] = f2bf(w2[c_orig * 128 + ch_out]);
    } else {                              // w3A: M=32 (mt 2), KS=4, permuted k
      int i3 = i - 24576;
      int j = i3 & 7, lane = (i3 >> 3) & 63, t = i3 >> 9;
      int mt = t >> 2, ks = t & 3;
      int ch_out = mt * 16 + (lane & 15);
      int kp = ks * 32 + (lane >> 4) * 8 + j;
      int c_orig = ((kp >> 2) & 7) * 16 + (kp >> 5) * 4 + (kp & 3);
      w3A[i3] = f2bf(w3[c_orig * 32 + ch_out]);
    }
    return;
  }
  i -= 28672;
  if (i < 147456) { convB_elem(mw1, cw1, i, 128, 4, 2); return; }
  i -= 147456;
  if (i < 147456) { convB_elem(mw2, cw2, i, 128, 4, 2); return; }
  i -= 147456;
  if (i < 73728)  { convB_elem(uw1, cu1, i, 128, 4, 1); return; }
  i -= 73728;
  if (i < 36864)  { convB_elem(uw2, cu2, i, 64, 4, 1); return; }
}

// ---------------- per-pixel dir-PE contribution: dconG[pixel][32] ----------------
__global__ __launch_bounds__(256) void dcon_kernel(
    const float* __restrict__ ray, const float* __restrict__ w3,
    const float* __restrict__ b3, float* __restrict__ dconG) {
  int gid = blockIdx.x * 256 + threadIdx.x;
  int pixel = gid >> 5, c = gid & 31;
  const float* r = ray + (size_t)pixel * 7;
  float d0 = r[3], d1 = r[4], d2 = r[5];
  float acc = b3[c];
  acc += d0 * w3[128 * 32 + c] + d1 * w3[129 * 32 + c] + d2 * w3[130 * 32 + c];
  float dv[3] = { d0, d1, d2 };
  #pragma unroll
  for (int cc = 0; cc < 3; ++cc) {
    float fs = 1.0f;
    #pragma unroll
    for (int f = 0; f < 4; ++f) {
      float s, co;
      __sincosf(dv[cc] * fs, &s, &co);
      acc += s * w3[(131 + cc * 4 + f) * 32 + c];
      acc += co * w3[(143 + cc * 4 + f) * 32 + c];
      fs *= 2.0f;
    }
  }
  dconG[gid] = acc;
}

// ---------------- fused per-sample MLP (R11: 64 samples/wave, mt-halved) -----
// Accepted local floor ~67 µs (5 structural variants R5-R11 all land 67±1).
__global__ __launch_bounds__(64, 3) void mlp_kernel(
    const float* __restrict__ zbufs, const float* __restrict__ ray,
    const int* __restrict__ isTrain,
    const float* __restrict__ b1, const float* __restrict__ b2,
    const unsigned short* __restrict__ w1A, const unsigned short* __restrict__ w2A,
    const unsigned short* __restrict__ w3A, const float* __restrict__ dconG,
    unsigned short* __restrict__ rdmp) {
  __shared__ __align__(16) unsigned short H[64 * 136];

  const int lane = threadIdx.x;
  const int q = lane >> 4, m = lane & 15;
  const float thresh = (isTrain[0] != 0) ? 0.2f : 0.0f;

  float fA[2], fB[2];
  int cAi[2], cBi[2];
  #pragma unroll
  for (int half = 0; half < 2; ++half) {
    int ch = half * 4 + q;
    cAi[half] = (ch <= 2) ? 0 : ((ch <= 4) ? 1 : 2);
    fA[half]  = (ch == 0 || ch == 5) ? 1.0f :
                (ch == 1 || ch == 6) ? 16.0f :
                (ch == 2 || ch == 7) ? 256.0f :
                (ch == 3) ? 4.0f : 64.0f;
    cBi[half] = (ch <= 1) ? 0 : ((ch <= 4) ? 1 : 2);
    fB[half]  = (ch == 2) ? 1.0f :
                (ch == 0 || ch == 5) ? 4.0f :
                (ch == 3) ? 16.0f :
                (ch == 1 || ch == 6) ? 64.0f : 256.0f;
  }

  bf16x8 bx[4][2];
  float zs[4];
  #pragma unroll
  for (int nt = 0; nt < 4; ++nt) {
    int s = nt * 16 + m;
    int sg = blockIdx.x * 64 + s;
    int pixel = sg >> 2;
    float z = zbufs[sg];
    zs[nt] = z;
    const float* r = ray + (size_t)pixel * 7;
    float t = z / r[6];
    float xv0 = r[0] + r[3] * t, xv1 = r[1] + r[4] * t, xv2 = r[2] + r[5] * t;
    #pragma unroll
    for (int half = 0; half < 2; ++half) {
      float uA = (cAi[half] == 0) ? xv0 : ((cAi[half] == 1) ? xv1 : xv2);
      float uB = (cBi[half] == 0) ? xv0 : ((cBi[half] == 1) ? xv1 : xv2);
      float sa, ca, sb, cb;
      __sincosf(uA * fA[half], &sa, &ca);
      __sincosf(uB * fB[half], &sb, &cb);
      float t2a = sa + sa;
      float sa1 = t2a * ca, ca1 = fmaf(-t2a, sa, 1.0f);
      float t2b = sb + sb;
      float sb1 = t2b * cb, cb1 = fmaf(-t2b, sb, 1.0f);
      if (half == 1 && q == 3) { sb = xv0; cb = xv1; sb1 = xv2; cb1 = 0.0f; }
      uint4 dv;
      dv.x = pk2bf(sa, ca); dv.y = pk2bf(sa1, ca1);
      dv.z = pk2bf(sb, cb); dv.w = pk2bf(sb1, cb1);
      bx[nt][half] = u4_to_bf(dv);
    }
  }

  // ---- layer 1: mt-halved ----
  #pragma unroll 1
  for (int half = 0; half < 2; ++half) {
    floatx4 acc[4][4];
    #pragma unroll
    for (int mt = 0; mt < 4; ++mt) {
      float4 bb = *reinterpret_cast<const float4*>(b1 + (half * 4 + mt) * 16 + q * 4);
      #pragma unroll
      for (int nt = 0; nt < 4; ++nt) {
        acc[mt][nt][0] = bb.x; acc[mt][nt][1] = bb.y;
        acc[mt][nt][2] = bb.z; acc[mt][nt][3] = bb.w;
      }
    }
    #pragma unroll
    for (int ks = 0; ks < 2; ++ks) {
      #pragma unroll
      for (int mt = 0; mt < 4; ++mt) {
        int mtg = half * 4 + mt;
        bf16x8 a = *reinterpret_cast<const bf16x8*>(w1A + (((mtg << 1) + ks) << 9) + lane * 8);
        #pragma unroll
        for (int nt = 0; nt < 4; ++nt)
          acc[mt][nt] = mfma16(a, bx[nt][ks], acc[mt][nt]);
      }
    }
    #pragma unroll
    for (int nt = 0; nt < 4; ++nt) {
      uint4* base = reinterpret_cast<uint4*>(&H[(nt * 16 + m) * 136 + q * 32 + half * 16]);
      #pragma unroll
      for (int g = 0; g < 2; ++g) {
        uint4 v;
        v.x = pk2bf(fmaxf(acc[2*g][nt][0], 0.0f),   fmaxf(acc[2*g][nt][1], 0.0f));
        v.y = pk2bf(fmaxf(acc[2*g][nt][2], 0.0f),   fmaxf(acc[2*g][nt][3], 0.0f));
        v.z = pk2bf(fmaxf(acc[2*g+1][nt][0], 0.0f), fmaxf(acc[2*g+1][nt][1], 0.0f));
        v.w = pk2bf(fmaxf(acc[2*g+1][nt][2], 0.0f), fmaxf(acc[2*g+1][nt][3], 0.0f));
        base[g] = v;
      }
    }
  }

  // ---- layer 2: mt-halved, half-0 epilogue staged in regs ----
  {
    uint4 keep[4][2];
    #pragma unroll 1
    for (int half = 0; half < 2; ++half) {
      floatx4 acc[4][4];
      #pragma unroll
      for (int mt = 0; mt < 4; ++mt) {
        float4 bb = *reinterpret_cast<const float4*>(b2 + (half * 4 + mt) * 16 + q * 4);
        #pragma unroll
        for (int nt = 0; nt < 4; ++nt) {
          acc[mt][nt][0] = bb.x; acc[mt][nt][1] = bb.y;
          acc[mt][nt][2] = bb.z; acc[mt][nt][3] = bb.w;
        }
      }
      #pragma unroll 1
      for (int ks = 0; ks < 4; ++ks) {
        bf16x8 bf[4];
        #pragma unroll
        for (int nt = 0; nt < 4; ++nt)
          bf[nt] = lds_frag(H + (nt * 16 + m) * 136 + ks * 32 + q * 8);
        #pragma unroll
        for (int mt = 0; mt < 4; ++mt) {
          int mtg = half * 4 + mt;
          bf16x8 a = *reinterpret_cast<const bf16x8*>(w2A + (((mtg << 2) + ks) << 9) + lane * 8);
          #pragma unroll
          for (int nt = 0; nt < 4; ++nt)
            acc[mt][nt] = mfma16(a, bf[nt], acc[mt][nt]);
        }
      }
      #pragma unroll
      for (int nt = 0; nt < 4; ++nt) {
        #pragma unroll
        for (int g = 0; g < 2; ++g) {
          uint4 v;
          v.x = pk2bf(fmaxf(acc[2*g][nt][0], 0.0f),   fmaxf(acc[2*g][nt][1], 0.0f));
          v.y = pk2bf(fmaxf(acc[2*g][nt][2], 0.0f),   fmaxf(acc[2*g][nt][3], 0.0f));
          v.z = pk2bf(fmaxf(acc[2*g+1][nt][0], 0.0f), fmaxf(acc[2*g+1][nt][1], 0.0f));
          v.w = pk2bf(fmaxf(acc[2*g+1][nt][2], 0.0f), fmaxf(acc[2*g+1][nt][3], 0.0f));
          if (half == 0) {
            keep[nt][g] = v;
          } else {
            *reinterpret_cast<uint4*>(&H[(nt * 16 + m) * 136 + q * 32 + 16 + g * 8]) = v;
          }
        }
      }
    }
    #pragma unroll
    for (int nt = 0; nt < 4; ++nt)
      #pragma unroll
      for (int g = 0; g < 2; ++g)
        *reinterpret_cast<uint4*>(&H[(nt * 16 + m) * 136 + q * 32 + g * 8]) = keep[nt][g];
  }

  // ---- layer 3 ----
  {
    floatx4 acc[2][4];
    const float* dg = dconG + (size_t)blockIdx.x * 512;
    #pragma unroll
    for (int nt = 0; nt < 4; ++nt) {
      int s = nt * 16 + m;
      #pragma unroll
      for (int mt = 0; mt < 2; ++mt)
        acc[mt][nt] = *reinterpret_cast<const floatx4*>(dg + (s >> 2) * 32 + mt * 16 + q * 4);
    }
    #pragma unroll 2
    for (int ks = 0; ks < 4; ++ks) {
      bf16x8 bf[4];
      #pragma unroll
      for (int nt = 0; nt < 4; ++nt)
        bf[nt] = lds_frag(H + (nt * 16 + m) * 136 + ks * 32 + q * 8);
      #pragma unroll
      for (int mt = 0; mt < 2; ++mt) {
        bf16x8 a = *reinterpret_cast<const bf16x8*>(w3A + (((mt << 2) + ks) << 9) + lane * 8);
        #pragma unroll
        for (int nt = 0; nt < 4; ++nt)
          acc[mt][nt] = mfma16(a, bf[nt], acc[mt][nt]);
      }
    }
    #pragma unroll
    for (int nt = 0; nt < 4; ++nt) {
      int s = nt * 16 + m;
      float mk = (zs[nt] > thresh) ? 1.0f : 0.0f;
      unsigned short* dst = rdmp + (size_t)blockIdx.x * 2048 + s * 32 + q * 4;
      #pragma unroll
      for (int mt = 0; mt < 2; ++mt) {
        uint2 pk;
        pk.x = pk2bf(acc[mt][nt][0] * mk, acc[mt][nt][1] * mk);
        pk.y = pk2bf(acc[mt][nt][2] * mk, acc[mt][nt][3] * mk);
        *reinterpret_cast<uint2*>(dst + mt * 16) = pk;
      }
    }
  }
}

// ---------------- NHWC 3x3 conv via MFMA, 16x8 tile, dx-outer ----------------
// R10 structure; MINW=3 raises occupancy 2->3 blocks/CU (VGPR cap 168; live
// ~145 est. — spill tripwire: symmetric FETCH/WRITE + VGPR<=90).
template<int CIN, int COUT, int MODE, int MINW>
__global__ __launch_bounds__(256, MINW) void conv3x3(
    const unsigned short* __restrict__ in, const unsigned short* __restrict__ wt,
    const float* __restrict__ bias, const unsigned short* __restrict__ rdmp,
    unsigned short* __restrict__ out) {
  constexpr int CP  = CIN + 8;
  constexpr int CH8 = CIN / 8;
  constexpr int KC  = CIN / 32;
  constexpr int NT  = COUT / 64;
  __shared__ __align__(16) unsigned short lds_in[10 * 18 * CP];

  const int tid = threadIdx.x;
  const int x0 = blockIdx.x * 16, y0 = blockIdx.y * 8;

  for (int i = tid; i < 180 * CH8; i += 256) {
    int pix = i / CH8, part = i - pix * CH8;
    int xx = pix % 18, yy = pix / 18;
    int gx = x0 - 1 + xx, gy = y0 - 1 + yy;
    ushort8 v = {0, 0, 0, 0, 0, 0, 0, 0};
    if (gx >= 0 && gx < IMGW && gy >= 0 && gy < IMGW)
      v = *reinterpret_cast<const ushort8*>(in + ((size_t)(gy * IMGW + gx)) * CIN + part * 8);
    *reinterpret_cast<ushort8*>(&lds_in[pix * CP + part * 8]) = v;
  }
  __syncthreads();

  const int wave = tid >> 6, lane = tid & 63, q = lane >> 4, m = lane & 15;
  floatx4 acc[8][NT] = {};

  #pragma unroll 1
  for (int kc = 0; kc < KC; ++kc) {
    #pragma unroll 1
    for (int dx = 0; dx < 3; ++dx) {
      bf16x8 a[10];
      #pragma unroll
      for (int rr = 0; rr < 10; ++rr)
        a[rr] = lds_frag(&lds_in[(rr * 18 + m + dx) * CP + kc * 32 + q * 8]);
      #pragma unroll
      for (int dy = 0; dy < 3; ++dy) {
        int ks = (dy * 3 + dx) * KC + kc;
        #pragma unroll
        for (int nt = 0; nt < NT; ++nt) {
          bf16x8 b = *reinterpret_cast<const bf16x8*>(
              wt + ((((size_t)ks * 4 + wave) * NT + nt) << 9) + lane * 8);
          #pragma unroll
          for (int mt = 0; mt < 8; ++mt)
            acc[mt][nt] = mfma16(a[mt + dy], b, acc[mt][nt]);
        }
      }
    }
  }

  const int co0 = wave * (COUT / 4);
  #pragma unroll
  for (int mt = 0; mt < 8; ++mt) {
    int y = y0 + mt;
    #pragma unroll
    for (int nt = 0; nt < NT; ++nt) {
      int co = co0 + nt * 16 + m;
      float bb = bias[co];
      #pragma unroll
      for (int r = 0; r < 4; ++r) {
        int pixel = y * IMGW + x0 + q * 4 + r;
        float v = acc[mt][nt][r] + bb;
        if (MODE == 0) {
          v = fmaxf(v, 0.0f);
        } else {
          v = 1.0f / (1.0f + __expf(-v));
          v *= bf2f(rdmp[(size_t)pixel * 128 + co]);
        }
        out[(size_t)pixel * COUT + co] = f2bf(v);
      }
    }
  }
}

// ---------------- final 64->3 conv + sigmoid, fp32 NHWC out ----------------
__global__ __launch_bounds__(256) void uconv3_kernel(
    const unsigned short* __restrict__ u2, const float* __restrict__ w,
    const float* __restrict__ b, float* __restrict__ out) {
  __shared__ float wl[1728];   // [nb][ci][c]
  for (int i = threadIdx.x; i < 1728; i += 256) {
    int c = i % 3; int t = i / 3; int ci = t & 63; int nb = t >> 6;
    wl[i] = w[(c * 64 + ci) * 9 + nb];
  }
  __syncthreads();
  int pixel = blockIdx.x * 256 + threadIdx.x;
  int py = pixel / IMGW, px = pixel - py * IMGW;
  float a0 = b[0], a1 = b[1], a2 = b[2];
  for (int nb = 0; nb < 9; ++nb) {
    int gy = py + nb / 3 - 1, gx = px + nb % 3 - 1;
    if (gx < 0 || gx >= IMGW || gy < 0 || gy >= IMGW) continue;
    const unsigned short* src = u2 + (size_t)(gy * IMGW + gx) * 64;
    const float* wp = wl + nb * 192;
    #pragma unroll
    for (int cc = 0; cc < 8; ++cc) {
      ushort8 v = *reinterpret_cast<const ushort8*>(src + cc * 8);
      #pragma unroll
      for (int j = 0; j < 8; ++j) {
        float uv = bf2f(v[j]);
        const float* w3p = wp + (cc * 8 + j) * 3;
        a0 += uv * w3p[0]; a1 += uv * w3p[1]; a2 += uv * w3p[2];
      }
    }
  }
  float* o = out + (size_t)pixel * 3;
  o[0] = 1.0f / (1.0f + __expf(-a0));
  o[1] = 1.0f / (1.0f + __expf(-a1));
  o[2] = 1.0f / (1.0f + __expf(-a2));
}

extern "C" void kernel_launch(void* const* d_in, const int* in_sizes, int n_in,
                              void* d_out, int out_size, void* d_ws, size_t ws_size,
                              hipStream_t stream) {
  (void)in_sizes; (void)n_in; (void)out_size; (void)ws_size;
  const float* zbufs = (const float*)d_in[0];
  const float* ray   = (const float*)d_in[1];
  const int* isTrain = (const int*)d_in[4];
  const float* w1 = (const float*)d_in[6];
  const float* b1 = (const float*)d_in[7];
  const float* w2 = (const float*)d_in[8];
  const float* b2 = (const float*)d_in[9];
  const float* w3 = (const float*)d_in[10];
  const float* b3 = (const float*)d_in[11];
  const float* mpn_w1 = (const float*)d_in[12];
  const float* mpn_b1 = (const float*)d_in[13];
  const float* mpn_w2 = (const float*)d_in[14];
  const float* mpn_b2 = (const float*)d_in[15];
  const float* uw1 = (const float*)d_in[16];
  const float* ub1 = (const float*)d_in[17];
  const float* uw2 = (const float*)d_in[18];
  const float* ub2 = (const float*)d_in[19];
  const float* uw3 = (const float*)d_in[20];
  const float* ub3 = (const float*)d_in[21];
  float* out = (float*)d_out;

  unsigned char* ws = (unsigned char*)d_ws;
  size_t off = 0;
  auto alloc = [&](size_t bytes) -> void* {
    void* p = ws + off; off = (off + bytes + 255) & ~(size_t)255; return p;
  };
  unsigned short* w1A  = (unsigned short*)alloc(8192 * 2);
  unsigned short* w2A  = (unsigned short*)alloc(16384 * 2);
  unsigned short* w3A  = (unsigned short*)alloc(4096 * 2);
  unsigned short* cw1  = (unsigned short*)alloc((size_t)128 * 1152 * 2);
  unsigned short* cw2  = (unsigned short*)alloc((size_t)128 * 1152 * 2);
  unsigned short* cu1  = (unsigned short*)alloc((size_t)64 * 1152 * 2);
  unsigned short* cu2  = (unsigned short*)alloc((size_t)64 * 576 * 2);
  unsigned short* rdmp = (unsigned short*)alloc((size_t)NPIX * 128 * 2);
  unsigned short* t1   = (unsigned short*)alloc((size_t)NPIX * 128 * 2);
  unsigned short* fuse = (unsigned short*)alloc((size_t)NPIX * 128 * 2);
  unsigned short* u1 = t1;            // t1 dead after conv2
  unsigned short* u2 = rdmp;          // rdmp dead after conv2 (fuse epilogue)
  float* dconG = (float*)fuse;        // dconG dead before conv2 writes fuse

  prep_all<<<1696, 256, 0, stream>>>(w1, w2, w3, mpn_w1, mpn_w2, uw1, uw2,
                                     w1A, w2A, w3A, cw1, cw2, cu1, cu2);
  dcon_kernel<<<NPIX * 32 / 256, 256, 0, stream>>>(ray, w3, b3, dconG);
  mlp_kernel<<<NPIX * 4 / 64, 64, 0, stream>>>(zbufs, ray, isTrain, b1, b2,
                                               w1A, w2A, w3A, dconG, rdmp);

  dim3 cgrid(IMGW / 16, IMGW / 8);
  conv3x3<128, 128, 0, 3><<<cgrid, 256, 0, stream>>>(rdmp, cw1, mpn_b1, nullptr, t1);
  conv3x3<128, 128, 1, 3><<<cgrid, 256, 0, stream>>>(t1, cw2, mpn_b2, rdmp, fuse);
  conv3x3<128, 64, 0, 3><<<cgrid, 256, 0, stream>>>(fuse, cu1, ub1, nullptr, u1);
  conv3x3<64, 64, 0, 3><<<cgrid, 256, 0, stream>>>(u1, cu2, ub2, nullptr, u2);
  uconv3_kernel<<<NPIX / 256, 256, 0, stream>>>(u2, uw3, ub3, out);
}

// Round 13
// 334.862 us; speedup vs baseline: 1.0748x; 1.0430x over previous
//
#include <hip/hip_runtime.h>
#include <hip/hip_bf16.h>
#include <math.h>

typedef __attribute__((ext_vector_type(8))) unsigned short ushort8;
typedef __attribute__((ext_vector_type(8))) __bf16 bf16x8;
typedef __attribute__((ext_vector_type(4))) float floatx4;

constexpr int IMGW = 384;
constexpr int NPIX = IMGW * IMGW;

__device__ __forceinline__ unsigned short f2bf(float f) {
  union { float f; unsigned u; } v; v.f = f;
  unsigned u = v.u;
  return (unsigned short)((u + 0x7fffu + ((u >> 16) & 1u)) >> 16);
}
__device__ __forceinline__ float bf2f(unsigned short h) {
  union { unsigned u; float f; } v; v.u = ((unsigned)h) << 16; return v.f;
}
// pack 2 fp32 -> 2 bf16 (RNE): v_cvt_pk_bf16_f32
__device__ __forceinline__ unsigned pk2bf(float a, float b) {
  float2 f2; f2.x = a; f2.y = b;
  __hip_bfloat162 h = __float22bfloat162_rn(f2);
  union { __hip_bfloat162 h; unsigned u; } u; u.h = h; return u.u;
}
__device__ __forceinline__ floatx4 mfma16(bf16x8 a, bf16x8 b, floatx4 c) {
  return __builtin_amdgcn_mfma_f32_16x16x32_bf16(a, b, c, 0, 0, 0);
}
__device__ __forceinline__ bf16x8 lds_frag(const unsigned short* p) {
  return *reinterpret_cast<const bf16x8*>(p);
}
__device__ __forceinline__ bf16x8 u4_to_bf(uint4 v) {
  union { uint4 u; bf16x8 b; } c; c.u = v; return c.b;
}

// ---------------- fused weight prep (single launch) ----------------
__device__ __forceinline__ void convB_elem(const float* __restrict__ w,
                                           unsigned short* __restrict__ wt,
                                           int i, int CIN, int G, int NT) {
  int j = i & 7, lane = (i >> 3) & 63;
  int rest = i >> 9;
  int nt = rest % NT; int rest2 = rest / NT;
  int g = rest2 % G;  int ks = rest2 / G;
  int q = lane >> 4, m = lane & 15;
  int co = (g * NT + nt) * 16 + m;
  int k = ks * 32 + q * 8 + j;
  int nb = k / CIN, ci = k - nb * CIN;
  wt[i] = f2bf(w[(co * CIN + ci) * 9 + nb]);
}

// jobs (linear index): [0,28672) mlpA | cw1 147456 | cw2 147456 | cu1 73728 | cu2 36864
__global__ __launch_bounds__(256) void prep_all(
    const float* __restrict__ w1, const float* __restrict__ w2, const float* __restrict__ w3,
    const float* __restrict__ mw1, const float* __restrict__ mw2,
    const float* __restrict__ uw1, const float* __restrict__ uw2,
    unsigned short* __restrict__ w1A, unsigned short* __restrict__ w2A,
    unsigned short* __restrict__ w3A,
    unsigned short* __restrict__ cw1, unsigned short* __restrict__ cw2,
    unsigned short* __restrict__ cu1, unsigned short* __restrict__ cu2) {
  int i = blockIdx.x * 256 + threadIdx.x;
  if (i < 28672) {
    if (i < 8192) {                       // w1A: M=128 (mt 8), KS=2
      int j = i & 7, lane = (i >> 3) & 63, t = i >> 9;
      int mt = t >> 1, ks = t & 1;
      int ch_out = mt * 16 + (lane & 15);
      int kp = ks * 32 + (lane >> 4) * 8 + j;
      int chunk = kp >> 3, sl = kp & 7;
      float val;
      if (chunk == 7 && sl >= 4) {
        int c = sl - 4;
        val = (c < 3) ? w1[c * 128 + ch_out] : 0.0f;   // raw x,y,z,pad
      } else {
        const int coordA[8] = {0,0,0,1,1,2,2,2};
        const int octA[8]   = {0,4,8,2,6,0,4,8};
        const int coordB[8] = {0,0,1,1,1,2,2,2};
        const int octB[8]   = {2,6,0,4,8,2,6,0};
        int rc  = (sl < 4) ? coordA[chunk] : coordB[chunk];
        int oct = ((sl < 4) ? octA[chunk] : octB[chunk]) + ((sl >> 1) & 1);
        int korig = ((sl & 1) ? 33 : 3) + rc * 10 + oct;
        val = w1[korig * 128 + ch_out];
      }
      w1A[i] = f2bf(val);
    } else if (i < 24576) {               // w2A: M=128 (mt 8), KS=4, permuted k
      int i2 = i - 8192;
      int j = i2 & 7, lane = (i2 >> 3) & 63, t = i2 >> 9;
      int mt = t >> 2, ks = t & 3;
      int ch_out = mt * 16 + (lane & 15);
      int kp = ks * 32 + (lane >> 4) * 8 + j;
      int c_orig = ((kp >> 2) & 7) * 16 + (kp >> 5) * 4 + (kp & 3);
      w2A[i2] = f2bf(w2[c_orig * 128 + ch_out]);
    } else {                              // w3A: M=32 (mt 2), KS=4, permuted k
      int i3 = i - 24576;
      int j = i3 & 7, lane = (i3 >> 3) & 63, t = i3 >> 9;
      int mt = t >> 2, ks = t & 3;
      int ch_out = mt * 16 + (lane & 15);
      int kp = ks * 32 + (lane >> 4) * 8 + j;
      int c_orig = ((kp >> 2) & 7) * 16 + (kp >> 5) * 4 + (kp & 3);
      w3A[i3] = f2bf(w3[c_orig * 32 + ch_out]);
    }
    return;
  }
  i -= 28672;
  if (i < 147456) { convB_elem(mw1, cw1, i, 128, 4, 2); return; }
  i -= 147456;
  if (i < 147456) { convB_elem(mw2, cw2, i, 128, 4, 2); return; }
  i -= 147456;
  if (i < 73728)  { convB_elem(uw1, cu1, i, 128, 4, 1); return; }
  i -= 73728;
  if (i < 36864)  { convB_elem(uw2, cu2, i, 64, 4, 1); return; }
}

// ---------------- per-pixel dir-PE contribution: dconG[pixel][32] ----------------
__global__ __launch_bounds__(256) void dcon_kernel(
    const float* __restrict__ ray, const float* __restrict__ w3,
    const float* __restrict__ b3, float* __restrict__ dconG) {
  int gid = blockIdx.x * 256 + threadIdx.x;
  int pixel = gid >> 5, c = gid & 31;
  const float* r = ray + (size_t)pixel * 7;
  float d0 = r[3], d1 = r[4], d2 = r[5];
  float acc = b3[c];
  acc += d0 * w3[128 * 32 + c] + d1 * w3[129 * 32 + c] + d2 * w3[130 * 32 + c];
  float dv[3] = { d0, d1, d2 };
  #pragma unroll
  for (int cc = 0; cc < 3; ++cc) {
    float fs = 1.0f;
    #pragma unroll
    for (int f = 0; f < 4; ++f) {
      float s, co;
      __sincosf(dv[cc] * fs, &s, &co);
      acc += s * w3[(131 + cc * 4 + f) * 32 + c];
      acc += co * w3[(143 + cc * 4 + f) * 32 + c];
      fs *= 2.0f;
    }
  }
  dconG[gid] = acc;
}

// ---------------- fused per-sample MLP (R11: 64 samples/wave, mt-halved) -----
// Accepted local floor ~66 µs (5 structural variants R5-R11 all land 67±1).
__global__ __launch_bounds__(64, 3) void mlp_kernel(
    const float* __restrict__ zbufs, const float* __restrict__ ray,
    const int* __restrict__ isTrain,
    const float* __restrict__ b1, const float* __restrict__ b2,
    const unsigned short* __restrict__ w1A, const unsigned short* __restrict__ w2A,
    const unsigned short* __restrict__ w3A, const float* __restrict__ dconG,
    unsigned short* __restrict__ rdmp) {
  __shared__ __align__(16) unsigned short H[64 * 136];

  const int lane = threadIdx.x;
  const int q = lane >> 4, m = lane & 15;
  const float thresh = (isTrain[0] != 0) ? 0.2f : 0.0f;

  float fA[2], fB[2];
  int cAi[2], cBi[2];
  #pragma unroll
  for (int half = 0; half < 2; ++half) {
    int ch = half * 4 + q;
    cAi[half] = (ch <= 2) ? 0 : ((ch <= 4) ? 1 : 2);
    fA[half]  = (ch == 0 || ch == 5) ? 1.0f :
                (ch == 1 || ch == 6) ? 16.0f :
                (ch == 2 || ch == 7) ? 256.0f :
                (ch == 3) ? 4.0f : 64.0f;
    cBi[half] = (ch <= 1) ? 0 : ((ch <= 4) ? 1 : 2);
    fB[half]  = (ch == 2) ? 1.0f :
                (ch == 0 || ch == 5) ? 4.0f :
                (ch == 3) ? 16.0f :
                (ch == 1 || ch == 6) ? 64.0f : 256.0f;
  }

  bf16x8 bx[4][2];
  float zs[4];
  #pragma unroll
  for (int nt = 0; nt < 4; ++nt) {
    int s = nt * 16 + m;
    int sg = blockIdx.x * 64 + s;
    int pixel = sg >> 2;
    float z = zbufs[sg];
    zs[nt] = z;
    const float* r = ray + (size_t)pixel * 7;
    float t = z / r[6];
    float xv0 = r[0] + r[3] * t, xv1 = r[1] + r[4] * t, xv2 = r[2] + r[5] * t;
    #pragma unroll
    for (int half = 0; half < 2; ++half) {
      float uA = (cAi[half] == 0) ? xv0 : ((cAi[half] == 1) ? xv1 : xv2);
      float uB = (cBi[half] == 0) ? xv0 : ((cBi[half] == 1) ? xv1 : xv2);
      float sa, ca, sb, cb;
      __sincosf(uA * fA[half], &sa, &ca);
      __sincosf(uB * fB[half], &sb, &cb);
      float t2a = sa + sa;
      float sa1 = t2a * ca, ca1 = fmaf(-t2a, sa, 1.0f);
      float t2b = sb + sb;
      float sb1 = t2b * cb, cb1 = fmaf(-t2b, sb, 1.0f);
      if (half == 1 && q == 3) { sb = xv0; cb = xv1; sb1 = xv2; cb1 = 0.0f; }
      uint4 dv;
      dv.x = pk2bf(sa, ca); dv.y = pk2bf(sa1, ca1);
      dv.z = pk2bf(sb, cb); dv.w = pk2bf(sb1, cb1);
      bx[nt][half] = u4_to_bf(dv);
    }
  }

  // ---- layer 1: mt-halved ----
  #pragma unroll 1
  for (int half = 0; half < 2; ++half) {
    floatx4 acc[4][4];
    #pragma unroll
    for (int mt = 0; mt < 4; ++mt) {
      float4 bb = *reinterpret_cast<const float4*>(b1 + (half * 4 + mt) * 16 + q * 4);
      #pragma unroll
      for (int nt = 0; nt < 4; ++nt) {
        acc[mt][nt][0] = bb.x; acc[mt][nt][1] = bb.y;
        acc[mt][nt][2] = bb.z; acc[mt][nt][3] = bb.w;
      }
    }
    #pragma unroll
    for (int ks = 0; ks < 2; ++ks) {
      #pragma unroll
      for (int mt = 0; mt < 4; ++mt) {
        int mtg = half * 4 + mt;
        bf16x8 a = *reinterpret_cast<const bf16x8*>(w1A + (((mtg << 1) + ks) << 9) + lane * 8);
        #pragma unroll
        for (int nt = 0; nt < 4; ++nt)
          acc[mt][nt] = mfma16(a, bx[nt][ks], acc[mt][nt]);
      }
    }
    #pragma unroll
    for (int nt = 0; nt < 4; ++nt) {
      uint4* base = reinterpret_cast<uint4*>(&H[(nt * 16 + m) * 136 + q * 32 + half * 16]);
      #pragma unroll
      for (int g = 0; g < 2; ++g) {
        uint4 v;
        v.x = pk2bf(fmaxf(acc[2*g][nt][0], 0.0f),   fmaxf(acc[2*g][nt][1], 0.0f));
        v.y = pk2bf(fmaxf(acc[2*g][nt][2], 0.0f),   fmaxf(acc[2*g][nt][3], 0.0f));
        v.z = pk2bf(fmaxf(acc[2*g+1][nt][0], 0.0f), fmaxf(acc[2*g+1][nt][1], 0.0f));
        v.w = pk2bf(fmaxf(acc[2*g+1][nt][2], 0.0f), fmaxf(acc[2*g+1][nt][3], 0.0f));
        base[g] = v;
      }
    }
  }

  // ---- layer 2: mt-halved, half-0 epilogue staged in regs ----
  {
    uint4 keep[4][2];
    #pragma unroll 1
    for (int half = 0; half < 2; ++half) {
      floatx4 acc[4][4];
      #pragma unroll
      for (int mt = 0; mt < 4; ++mt) {
        float4 bb = *reinterpret_cast<const float4*>(b2 + (half * 4 + mt) * 16 + q * 4);
        #pragma unroll
        for (int nt = 0; nt < 4; ++nt) {
          acc[mt][nt][0] = bb.x; acc[mt][nt][1] = bb.y;
          acc[mt][nt][2] = bb.z; acc[mt][nt][3] = bb.w;
        }
      }
      #pragma unroll 1
      for (int ks = 0; ks < 4; ++ks) {
        bf16x8 bf[4];
        #pragma unroll
        for (int nt = 0; nt < 4; ++nt)
          bf[nt] = lds_frag(H + (nt * 16 + m) * 136 + ks * 32 + q * 8);
        #pragma unroll
        for (int mt = 0; mt < 4; ++mt) {
          int mtg = half * 4 + mt;
          bf16x8 a = *reinterpret_cast<const bf16x8*>(w2A + (((mtg << 2) + ks) << 9) + lane * 8);
          #pragma unroll
          for (int nt = 0; nt < 4; ++nt)
            acc[mt][nt] = mfma16(a, bf[nt], acc[mt][nt]);
        }
      }
      #pragma unroll
      for (int nt = 0; nt < 4; ++nt) {
        #pragma unroll
        for (int g = 0; g < 2; ++g) {
          uint4 v;
          v.x = pk2bf(fmaxf(acc[2*g][nt][0], 0.0f),   fmaxf(acc[2*g][nt][1], 0.0f));
          v.y = pk2bf(fmaxf(acc[2*g][nt][2], 0.0f),   fmaxf(acc[2*g][nt][3], 0.0f));
          v.z = pk2bf(fmaxf(acc[2*g+1][nt][0], 0.0f), fmaxf(acc[2*g+1][nt][1], 0.0f));
          v.w = pk2bf(fmaxf(acc[2*g+1][nt][2], 0.0f), fmaxf(acc[2*g+1][nt][3], 0.0f));
          if (half == 0) {
            keep[nt][g] = v;
          } else {
            *reinterpret_cast<uint4*>(&H[(nt * 16 + m) * 136 + q * 32 + 16 + g * 8]) = v;
          }
        }
      }
    }
    #pragma unroll
    for (int nt = 0; nt < 4; ++nt)
      #pragma unroll
      for (int g = 0; g < 2; ++g)
        *reinterpret_cast<uint4*>(&H[(nt * 16 + m) * 136 + q * 32 + g * 8]) = keep[nt][g];
  }

  // ---- layer 3 ----
  {
    floatx4 acc[2][4];
    const float* dg = dconG + (size_t)blockIdx.x * 512;
    #pragma unroll
    for (int nt = 0; nt < 4; ++nt) {
      int s = nt * 16 + m;
      #pragma unroll
      for (int mt = 0; mt < 2; ++mt)
        acc[mt][nt] = *reinterpret_cast<const floatx4*>(dg + (s >> 2) * 32 + mt * 16 + q * 4);
    }
    #pragma unroll 2
    for (int ks = 0; ks < 4; ++ks) {
      bf16x8 bf[4];
      #pragma unroll
      for (int nt = 0; nt < 4; ++nt)
        bf[nt] = lds_frag(H + (nt * 16 + m) * 136 + ks * 32 + q * 8);
      #pragma unroll
      for (int mt = 0; mt < 2; ++mt) {
        bf16x8 a = *reinterpret_cast<const bf16x8*>(w3A + (((mt << 2) + ks) << 9) + lane * 8);
        #pragma unroll
        for (int nt = 0; nt < 4; ++nt)
          acc[mt][nt] = mfma16(a, bf[nt], acc[mt][nt]);
      }
    }
    #pragma unroll
    for (int nt = 0; nt < 4; ++nt) {
      int s = nt * 16 + m;
      float mk = (zs[nt] > thresh) ? 1.0f : 0.0f;
      unsigned short* dst = rdmp + (size_t)blockIdx.x * 2048 + s * 32 + q * 4;
      #pragma unroll
      for (int mt = 0; mt < 2; ++mt) {
        uint2 pk;
        pk.x = pk2bf(acc[mt][nt][0] * mk, acc[mt][nt][1] * mk);
        pk.y = pk2bf(acc[mt][nt][2] * mk, acc[mt][nt][3] * mk);
        *reinterpret_cast<uint2*>(dst + mt * 16) = pk;
      }
    }
  }
}

// ---------------- NHWC 3x3 conv via MFMA, 16x8 tile, B double-buffered -------
// R12 theory: rolled (kc,dx) loop serialized 300-cyc L2 B-load stall against
// 770-cyc MFMA burst (~28% duty). Fix: prefetch group g+1's B-fragments into
// bnxt while group g's MFMAs run; the vmcnt wait lands on the register copy
// AFTER the MFMA burst. B regs 2x3xNTx4; live set NT=2 ~164 -> MINW=2.
template<int CIN, int COUT, int MODE, int MINW>
__global__ __launch_bounds__(256, MINW) void conv3x3(
    const unsigned short* __restrict__ in, const unsigned short* __restrict__ wt,
    const float* __restrict__ bias, const unsigned short* __restrict__ rdmp,
    unsigned short* __restrict__ out) {
  constexpr int CP  = CIN + 8;
  constexpr int CH8 = CIN / 8;
  constexpr int KC  = CIN / 32;
  constexpr int NT  = COUT / 64;
  constexpr int GROUPS = KC * 3;
  __shared__ __align__(16) unsigned short lds_in[10 * 18 * CP];

  const int tid = threadIdx.x;
  const int x0 = blockIdx.x * 16, y0 = blockIdx.y * 8;

  for (int i = tid; i < 180 * CH8; i += 256) {
    int pix = i / CH8, part = i - pix * CH8;
    int xx = pix % 18, yy = pix / 18;
    int gx = x0 - 1 + xx, gy = y0 - 1 + yy;
    ushort8 v = {0, 0, 0, 0, 0, 0, 0, 0};
    if (gx >= 0 && gx < IMGW && gy >= 0 && gy < IMGW)
      v = *reinterpret_cast<const ushort8*>(in + ((size_t)(gy * IMGW + gx)) * CIN + part * 8);
    *reinterpret_cast<ushort8*>(&lds_in[pix * CP + part * 8]) = v;
  }
  __syncthreads();

  const int wave = tid >> 6, lane = tid & 63, q = lane >> 4, m = lane & 15;
  floatx4 acc[8][NT] = {};

  auto loadB = [&](int g, bf16x8 (&bb)[3][NT]) {
    int kc = g / 3, dx = g - kc * 3;
    #pragma unroll
    for (int dy = 0; dy < 3; ++dy) {
      int ks = (dy * 3 + dx) * KC + kc;
      #pragma unroll
      for (int nt = 0; nt < NT; ++nt)
        bb[dy][nt] = *reinterpret_cast<const bf16x8*>(
            wt + ((((size_t)ks * 4 + wave) * NT + nt) << 9) + lane * 8);
    }
  };

  bf16x8 bcur[3][NT], bnxt[3][NT];
  loadB(0, bcur);

  #pragma unroll 1
  for (int g = 0; g < GROUPS; ++g) {
    if (g + 1 < GROUPS) loadB(g + 1, bnxt);     // in-flight during MFMAs below
    int kc = g / 3, dx = g - kc * 3;
    bf16x8 a[10];
    #pragma unroll
    for (int rr = 0; rr < 10; ++rr)
      a[rr] = lds_frag(&lds_in[(rr * 18 + m + dx) * CP + kc * 32 + q * 8]);
    #pragma unroll
    for (int dy = 0; dy < 3; ++dy)
      #pragma unroll
      for (int nt = 0; nt < NT; ++nt)
        #pragma unroll
        for (int mt = 0; mt < 8; ++mt)
          acc[mt][nt] = mfma16(a[mt + dy], bcur[dy][nt], acc[mt][nt]);
    #pragma unroll
    for (int dy = 0; dy < 3; ++dy)
      #pragma unroll
      for (int nt = 0; nt < NT; ++nt)
        bcur[dy][nt] = bnxt[dy][nt];            // vmcnt wait lands here
  }

  const int co0 = wave * (COUT / 4);
  #pragma unroll
  for (int mt = 0; mt < 8; ++mt) {
    int y = y0 + mt;
    #pragma unroll
    for (int nt = 0; nt < NT; ++nt) {
      int co = co0 + nt * 16 + m;
      float bb = bias[co];
      #pragma unroll
      for (int r = 0; r < 4; ++r) {
        int pixel = y * IMGW + x0 + q * 4 + r;
        float v = acc[mt][nt][r] + bb;
        if (MODE == 0) {
          v = fmaxf(v, 0.0f);
        } else {
          v = 1.0f / (1.0f + __expf(-v));
          v *= bf2f(rdmp[(size_t)pixel * 128 + co]);
        }
        out[(size_t)pixel * COUT + co] = f2bf(v);
      }
    }
  }
}

// ---------------- final 64->3 conv + sigmoid, fp32 NHWC out ----------------
__global__ __launch_bounds__(256) void uconv3_kernel(
    const unsigned short* __restrict__ u2, const float* __restrict__ w,
    const float* __restrict__ b, float* __restrict__ out) {
  __shared__ float wl[1728];   // [nb][ci][c]
  for (int i = threadIdx.x; i < 1728; i += 256) {
    int c = i % 3; int t = i / 3; int ci = t & 63; int nb = t >> 6;
    wl[i] = w[(c * 64 + ci) * 9 + nb];
  }
  __syncthreads();
  int pixel = blockIdx.x * 256 + threadIdx.x;
  int py = pixel / IMGW, px = pixel - py * IMGW;
  float a0 = b[0], a1 = b[1], a2 = b[2];
  for (int nb = 0; nb < 9; ++nb) {
    int gy = py + nb / 3 - 1, gx = px + nb % 3 - 1;
    if (gx < 0 || gx >= IMGW || gy < 0 || gy >= IMGW) continue;
    const unsigned short* src = u2 + (size_t)(gy * IMGW + gx) * 64;
    const float* wp = wl + nb * 192;
    #pragma unroll
    for (int cc = 0; cc < 8; ++cc) {
      ushort8 v = *reinterpret_cast<const ushort8*>(src + cc * 8);
      #pragma unroll
      for (int j = 0; j < 8; ++j) {
        float uv = bf2f(v[j]);
        const float* w3p = wp + (cc * 8 + j) * 3;
        a0 += uv * w3p[0]; a1 += uv * w3p[1]; a2 += uv * w3p[2];
      }
    }
  }
  float* o = out + (size_t)pixel * 3;
  o[0] = 1.0f / (1.0f + __expf(-a0));
  o[1] = 1.0f / (1.0f + __expf(-a1));
  o[2] = 1.0f / (1.0f + __expf(-a2));
}

extern "C" void kernel_launch(void* const* d_in, const int* in_sizes, int n_in,
                              void* d_out, int out_size, void* d_ws, size_t ws_size,
                              hipStream_t stream) {
  (void)in_sizes; (void)n_in; (void)out_size; (void)ws_size;
  const float* zbufs = (const float*)d_in[0];
  const float* ray   = (const float*)d_in[1];
  const int* isTrain = (const int*)d_in[4];
  const float* w1 = (const float*)d_in[6];
  const float* b1 = (const float*)d_in[7];
  const float* w2 = (const float*)d_in[8];
  const float* b2 = (const float*)d_in[9];
  const float* w3 = (const float*)d_in[10];
  const float* b3 = (const float*)d_in[11];
  const float* mpn_w1 = (const float*)d_in[12];
  const float* mpn_b1 = (const float*)d_in[13];
  const float* mpn_w2 = (const float*)d_in[14];
  const float* mpn_b2 = (const float*)d_in[15];
  const float* uw1 = (const float*)d_in[16];
  const float* ub1 = (const float*)d_in[17];
  const float* uw2 = (const float*)d_in[18];
  const float* ub2 = (const float*)d_in[19];
  const float* uw3 = (const float*)d_in[20];
  const float* ub3 = (const float*)d_in[21];
  float* out = (float*)d_out;

  unsigned char* ws = (unsigned char*)d_ws;
  size_t off = 0;
  auto alloc = [&](size_t bytes) -> void* {
    void* p = ws + off; off = (off + bytes + 255) & ~(size_t)255; return p;
  };
  unsigned short* w1A  = (unsigned short*)alloc(8192 * 2);
  unsigned short* w2A  = (unsigned short*)alloc(16384 * 2);
  unsigned short* w3A  = (unsigned short*)alloc(4096 * 2);
  unsigned short* cw1  = (unsigned short*)alloc((size_t)128 * 1152 * 2);
  unsigned short* cw2  = (unsigned short*)alloc((size_t)128 * 1152 * 2);
  unsigned short* cu1  = (unsigned short*)alloc((size_t)64 * 1152 * 2);
  unsigned short* cu2  = (unsigned short*)alloc((size_t)64 * 576 * 2);
  unsigned short* rdmp = (unsigned short*)alloc((size_t)NPIX * 128 * 2);
  unsigned short* t1   = (unsigned short*)alloc((size_t)NPIX * 128 * 2);
  unsigned short* fuse = (unsigned short*)alloc((size_t)NPIX * 128 * 2);
  unsigned short* u1 = t1;            // t1 dead after conv2
  unsigned short* u2 = rdmp;          // rdmp dead after conv2 (fuse epilogue)
  float* dconG = (float*)fuse;        // dconG dead before conv2 writes fuse

  prep_all<<<1696, 256, 0, stream>>>(w1, w2, w3, mpn_w1, mpn_w2, uw1, uw2,
                                     w1A, w2A, w3A, cw1, cw2, cu1, cu2);
  dcon_kernel<<<NPIX * 32 / 256, 256, 0, stream>>>(ray, w3, b3, dconG);
  mlp_kernel<<<NPIX * 4 / 64, 64, 0, stream>>>(zbufs, ray, isTrain, b1, b2,
                                               w1A, w2A, w3A, dconG, rdmp);

  dim3 cgrid(IMGW / 16, IMGW / 8);
  conv3x3<128, 128, 0, 2><<<cgrid, 256, 0, stream>>>(rdmp, cw1, mpn_b1, nullptr, t1);
  conv3x3<128, 128, 1, 2><<<cgrid, 256, 0, stream>>>(t1, cw2, mpn_b2, rdmp, fuse);
  conv3x3<128, 64, 0, 3><<<cgrid, 256, 0, stream>>>(fuse, cu1, ub1, nullptr, u1);
  conv3x3<64, 64, 0, 3><<<cgrid, 256, 0, stream>>>(u1, cu2, ub2, nullptr, u2);
  uconv3_kernel<<<NPIX / 256, 256, 0, stream>>>(u2, uw3, ub3, out);
}